// Round 10
// baseline (598.578 us; speedup 1.0000x reference)
//
#include <hip/hip_runtime.h>
#include <hip/hip_bf16.h>

typedef unsigned short ushort_t;
typedef __attribute__((ext_vector_type(8))) short short8;
typedef __attribute__((ext_vector_type(4))) float f32x4;

#define M_DIM 8192
#define N_DIM 8192
#define K_DIM 2048
#define BM 256
#define BN 256
#define BK 64
#define NT (K_DIM / BK)   // 32 K-tiles

__device__ __forceinline__ ushort_t f2bf(float f) {
    union { float f; unsigned u; } v; v.f = f;
    unsigned r = v.u + 0x7fffu + ((v.u >> 16) & 1u);   // RNE
    return (ushort_t)(r >> 16);
}

__device__ __forceinline__ void async_copy16(const void* g, void* l) {
    __builtin_amdgcn_global_load_lds(
        (const __attribute__((address_space(1))) void*)g,
        (__attribute__((address_space(3))) void*)l, 16, 0, 0);
}

#define BAR() __builtin_amdgcn_s_barrier()
#define LGKM(n) do { asm volatile("s_waitcnt lgkmcnt(" #n ")" ::: "memory"); \
                     __builtin_amdgcn_sched_barrier(0); } while (0)

// ---- kernel 1: x (f32) -> A (bf16) ----
__global__ __launch_bounds__(256) void convert_x(const float* __restrict__ x,
                                                 ushort_t* __restrict__ A) {
    int t = blockIdx.x * 256 + threadIdx.x;
    const float4* p = (const float4*)x + (size_t)t * 2;
    float4 a = p[0], b = p[1];
    short8 o;
    o[0] = (short)f2bf(a.x); o[1] = (short)f2bf(a.y);
    o[2] = (short)f2bf(a.z); o[3] = (short)f2bf(a.w);
    o[4] = (short)f2bf(b.x); o[5] = (short)f2bf(b.y);
    o[6] = (short)f2bf(b.z); o[7] = (short)f2bf(b.w);
    *(short8*)(A + (size_t)t * 8) = o;
}

// ---- kernel 2: codebook gather -> Bt (bf16, N x K layout) ----
__global__ __launch_bounds__(256) void dequant_wt(const int* __restrict__ indices,
                                                  const float* __restrict__ codebook,
                                                  ushort_t* __restrict__ Bt) {
    int g = blockIdx.x;                       // column group 0..1023
    int i = blockIdx.y * 256 + threadIdx.x;   // K row 0..2047
    int idx = indices[(size_t)i * 1024 + g];
    const float4* cb = (const float4*)(codebook + (size_t)idx * 8);
    float4 lo = cb[0], hi = cb[1];
    size_t base = (size_t)g * 8 * K_DIM + i;
    Bt[base + 0 * K_DIM] = f2bf(lo.x);
    Bt[base + 1 * K_DIM] = f2bf(lo.y);
    Bt[base + 2 * K_DIM] = f2bf(lo.z);
    Bt[base + 3 * K_DIM] = f2bf(lo.w);
    Bt[base + 4 * K_DIM] = f2bf(hi.x);
    Bt[base + 5 * K_DIM] = f2bf(hi.y);
    Bt[base + 6 * K_DIM] = f2bf(hi.z);
    Bt[base + 7 * K_DIM] = f2bf(hi.w);
}

// ---- helpers ----
// read a 64x64 sub-half: 4 m/n-frags x 2 k-granule-pairs (8 x ds_read_b128)
__device__ __forceinline__ void read_f(const char* p, int rd, short8 (&fr)[4][2]) {
#pragma unroll
    for (int i = 0; i < 4; ++i) {
        fr[i][0] = *(const short8*)(p + rd + i * 2048);
        fr[i][1] = *(const short8*)(p + (rd ^ 64) + i * 2048);
    }
}

__device__ __forceinline__ void mfma32(const short8 (&af)[4][2], const short8 (&bf)[4][2],
                                       f32x4 (&acc)[8][8], int I0, int J0) {
    __builtin_amdgcn_s_setprio(1);
#pragma unroll
    for (int kk = 0; kk < 2; ++kk)
#pragma unroll
        for (int i = 0; i < 4; ++i)
#pragma unroll
            for (int j = 0; j < 4; ++j)
                acc[I0 + i][J0 + j] = __builtin_amdgcn_mfma_f32_16x16x32_bf16(
                    af[i][kk], bf[j][kk], acc[I0 + i][J0 + j], 0, 0, 0);
    __builtin_amdgcn_s_setprio(0);
}

// ---- kernel 3: C = A(MxK)*Bt(NxK)^T + bias ; 256^2 tile, 4 waves, 1 wave/SIMD ----
// R10: 512-VGPR/wave budget -> full one-phase read-ahead (no MFMA waits on
// same-phase reads), R8's 4-barrier skeleton and stage/vmcnt ledger.
__global__ __launch_bounds__(256, 1) void gemm_256_pipe4(const ushort_t* __restrict__ A,
                                                         const ushort_t* __restrict__ Bt,
                                                         const float* __restrict__ bias,
                                                         float* __restrict__ C) {
    __shared__ __align__(16) ushort_t lds_a[2][2][128 * 64];   // [dbuf][half][.]
    __shared__ __align__(16) ushort_t lds_b[2][2][128 * 64];

    // 2D XCD-rectangle swizzle (R5)
    const int bid = blockIdx.x;                  // 0..1023
    const int xc = bid & 7;                      // XCD
    const int qq = bid >> 3;                     // 0..127
    const int mt = ((xc >> 1) << 2) + (qq & 3) + (((qq >> 5) & 1) << 4);
    const int nt = ((xc & 1) << 3) + ((qq >> 2) & 7) + (((qq >> 6) & 1) << 4);
    const int m0 = mt * BM;
    const int n0 = nt * BN;

    const int tid = threadIdx.x;
    const int lane = tid & 63;
    const int wid = tid >> 6;              // 0..3
    const int wm = wid >> 1, wn = wid & 1; // 2x2 wave grid; wave out 128x128
    const int lane15 = lane & 15, laneq = lane >> 4;
    const int xa = lane15 & 7;
    const int rdk = lane15 * 128 + ((laneq ^ xa) << 4);   // frag read base

    // --- staging addresses: thread covers granules {t, t+256, t+512, t+768} ---
    const int r0 = tid >> 3;                      // 0..31
    const int c0 = (tid & 7) ^ (r0 & 7);          // inverse-swizzled k-granule
    const ushort_t* Ab = A  + (size_t)(m0 + r0) * K_DIM + c0 * 8;
    const ushort_t* Bb = Bt + (size_t)(n0 + r0) * K_DIM + c0 * 8;
    const int dq = tid * 16;
    const size_t HOFF = (size_t)128 * K_DIM;

#define STAGE_A(gt, hh) do { \
        char* _d = (char*)&lds_a[(gt) & 1][hh][0] + dq; \
        const ushort_t* _g = Ab + (size_t)(hh) * HOFF + (size_t)(gt) * BK; \
        async_copy16(_g,                      _d); \
        async_copy16(_g + (size_t)32 * K_DIM, _d + 4096); \
        async_copy16(_g + (size_t)64 * K_DIM, _d + 8192); \
        async_copy16(_g + (size_t)96 * K_DIM, _d + 12288); \
    } while (0)
#define STAGE_B(gt, hh) do { \
        char* _d = (char*)&lds_b[(gt) & 1][hh][0] + dq; \
        const ushort_t* _g = Bb + (size_t)(hh) * HOFF + (size_t)(gt) * BK; \
        async_copy16(_g,                      _d); \
        async_copy16(_g + (size_t)32 * K_DIM, _d + 4096); \
        async_copy16(_g + (size_t)64 * K_DIM, _d + 8192); \
        async_copy16(_g + (size_t)96 * K_DIM, _d + 12288); \
    } while (0)

    f32x4 acc[8][8];
#pragma unroll
    for (int i = 0; i < 8; ++i)
#pragma unroll
        for (int j = 0; j < 8; ++j) acc[i][j] = (f32x4){0.f, 0.f, 0.f, 0.f};

    short8 afX[4][2], afY[4][2], bf1[4][2], bfE[4][2], bfO[4][2];

    // --- prologue: tile0 + B(1); then first-phase fragments ---
    STAGE_A(0, 0); STAGE_A(0, 1); STAGE_B(0, 0); STAGE_B(0, 1);
    STAGE_B(1, 0); STAGE_B(1, 1);
    asm volatile("s_waitcnt vmcnt(8)" ::: "memory");   // tile0 resident; B(1) in flight
    BAR();
    read_f((const char*)&lds_a[0][wm][0], rdk, afX);   // A0(0)
    read_f((const char*)&lds_b[0][wn][0], rdk, bfE);   // B0(0)

    // Phase ledger (per iter g, parity d=g&1):
    //  P1: mfma(afX,bfc @ m0n0) | read B1(g)->bf1   | stage A(g+1) both halves
    //  P2: mfma(afX,bf1 @ m0n1) | read A1(g)->afY
    //  P3: mfma(afY,bf1 @ m1n1) |                   | stage B(g+2,0)
    //  P4: mfma(afY,bfc @ m1n0) | vmcnt(8); read A0/B0(g+1)->afX,bfn | stage B(g+2,1)
    // lgkm: P1 (8) retires prev-P4's 16, leaves bf1; P2 (8) retires bf1,
    // leaves afY; P3 (0) retires afY; P4 none. vmcnt(8) retires tile g+1.
#define ITER(g, bfc, bfn) do { \
        const int d = (g) & 1; \
        const char* sa = (const char*)&lds_a[d][wm][0]; \
        const char* sb = (const char*)&lds_b[d][wn][0]; \
        /* P1 */ \
        read_f(sb + 8192, rdk, bf1); \
        if ((g) + 1 < NT) { STAGE_A((g) + 1, 0); STAGE_A((g) + 1, 1); } \
        BAR(); LGKM(8); \
        mfma32(afX, bfc, acc, 0, 0); \
        /* P2 */ \
        read_f(sa + 8192, rdk, afY); \
        BAR(); LGKM(8); \
        mfma32(afX, bf1, acc, 0, 4); \
        /* P3 */ \
        if ((g) + 2 < NT) STAGE_B((g) + 2, 0); \
        BAR(); LGKM(0); \
        mfma32(afY, bf1, acc, 4, 4); \
        /* P4 */ \
        if ((g) + 2 < NT) STAGE_B((g) + 2, 1); \
        if ((g) < NT - 2) { asm volatile("s_waitcnt vmcnt(8)" ::: "memory"); } \
        else              { asm volatile("s_waitcnt vmcnt(0)" ::: "memory"); } \
        __builtin_amdgcn_sched_barrier(0); \
        if ((g) + 1 < NT) { \
            read_f((const char*)&lds_a[1 - d][wm][0], rdk, afX); \
            read_f((const char*)&lds_b[1 - d][wn][0], rdk, bfn); \
        } \
        BAR(); \
        mfma32(afY, bfc, acc, 4, 0); \
    } while (0)

    for (int g = 0; g < NT; g += 2) {
        ITER(g, bfE, bfO);
        ITER(g + 1, bfO, bfE);
    }
#undef ITER

    // --- epilogue: bias + f32 store ---
#pragma unroll
    for (int jg = 0; jg < 8; ++jg) {
        const int col = n0 + wn * 128 + jg * 16 + lane15;
        const float bv = bias[col];
#pragma unroll
        for (int ig = 0; ig < 8; ++ig) {
            const int row = m0 + wm * 128 + ig * 16 + laneq * 4;
            f32x4 v = acc[ig][jg];
#pragma unroll
            for (int q2 = 0; q2 < 4; ++q2)
                C[(size_t)(row + q2) * N_DIM + col] = v[q2] + bv;
        }
    }
#undef STAGE_A
#undef STAGE_B
}

extern "C" void kernel_launch(void* const* d_in, const int* in_sizes, int n_in,
                              void* d_out, int out_size, void* d_ws, size_t ws_size,
                              hipStream_t stream) {
    const float* x = (const float*)d_in[0];
    const float* codebook = (const float*)d_in[1];
    const int* indices = (const int*)d_in[2];      // harness: integer -> int32
    const float* bias = (const float*)d_in[3];
    float* out = (float*)d_out;

    ushort_t* A  = (ushort_t*)d_ws;                               // 32 MB
    ushort_t* Bt = (ushort_t*)d_ws + (size_t)M_DIM * K_DIM;       // 32 MB

    convert_x<<<dim3(M_DIM * K_DIM / (256 * 8)), 256, 0, stream>>>(x, A);
    dequant_wt<<<dim3(1024, 8), 256, 0, stream>>>(indices, codebook, Bt);
    gemm_256_pipe4<<<dim3((M_DIM / BM) * (N_DIM / BN)), 256, 0, stream>>>(A, Bt, bias, out);
}

// Round 12
// 335.584 us; speedup vs baseline: 1.7837x; 1.7837x over previous
//
#include <hip/hip_runtime.h>
#include <hip/hip_bf16.h>

typedef unsigned short ushort_t;
typedef __attribute__((ext_vector_type(8))) short short8;
typedef __attribute__((ext_vector_type(4))) float f32x4;

#define M_DIM 8192
#define N_DIM 8192
#define K_DIM 2048
#define BM 256
#define BN 256
#define BK 32
#define NT (K_DIM / BK)        // 64 K-tiles
#define SLOT (BM * BK)         // 8192 bf16 = 16 KiB per operand slot
#define KROW64 ((size_t)64 * K_DIM)

__device__ __forceinline__ ushort_t f2bf(float f) {
    union { float f; unsigned u; } v; v.f = f;
    unsigned r = v.u + 0x7fffu + ((v.u >> 16) & 1u);   // RNE
    return (ushort_t)(r >> 16);
}

__device__ __forceinline__ void async_copy16(const void* g, void* l) {
    __builtin_amdgcn_global_load_lds(
        (const __attribute__((address_space(1))) void*)g,
        (__attribute__((address_space(3))) void*)l, 16, 0, 0);
}

#define BAR() __builtin_amdgcn_s_barrier()
// lgkmcnt is a 4-bit field (max 15). DS ops retire in order: waiting to <=15
// with 16 prev + 16 new outstanding retires all 16 prev (+ at most 1 new).
#define LGKM(n) do { asm volatile("s_waitcnt lgkmcnt(" #n ")" ::: "memory"); \
                     __builtin_amdgcn_sched_barrier(0); } while (0)
#define VMC(n) asm volatile("s_waitcnt vmcnt(" #n ")" ::: "memory")

// ---- kernel 1: x (f32) -> A (bf16) ----
__global__ __launch_bounds__(256) void convert_x(const float* __restrict__ x,
                                                 ushort_t* __restrict__ A) {
    int t = blockIdx.x * 256 + threadIdx.x;
    const float4* p = (const float4*)x + (size_t)t * 2;
    float4 a = p[0], b = p[1];
    short8 o;
    o[0] = (short)f2bf(a.x); o[1] = (short)f2bf(a.y);
    o[2] = (short)f2bf(a.z); o[3] = (short)f2bf(a.w);
    o[4] = (short)f2bf(b.x); o[5] = (short)f2bf(b.y);
    o[6] = (short)f2bf(b.z); o[7] = (short)f2bf(b.w);
    *(short8*)(A + (size_t)t * 8) = o;
}

// ---- kernel 2: codebook gather -> Bt (bf16, N x K layout) ----
__global__ __launch_bounds__(256) void dequant_wt(const int* __restrict__ indices,
                                                  const float* __restrict__ codebook,
                                                  ushort_t* __restrict__ Bt) {
    int g = blockIdx.x;                       // column group 0..1023
    int i = blockIdx.y * 256 + threadIdx.x;   // K row 0..2047
    int idx = indices[(size_t)i * 1024 + g];
    const float4* cb = (const float4*)(codebook + (size_t)idx * 8);
    float4 lo = cb[0], hi = cb[1];
    size_t base = (size_t)g * 8 * K_DIM + i;
    Bt[base + 0 * K_DIM] = f2bf(lo.x);
    Bt[base + 1 * K_DIM] = f2bf(lo.y);
    Bt[base + 2 * K_DIM] = f2bf(lo.z);
    Bt[base + 3 * K_DIM] = f2bf(lo.w);
    Bt[base + 4 * K_DIM] = f2bf(hi.x);
    Bt[base + 5 * K_DIM] = f2bf(hi.y);
    Bt[base + 6 * K_DIM] = f2bf(hi.z);
    Bt[base + 7 * K_DIM] = f2bf(hi.w);
}

// ---- helpers ----
__device__ __forceinline__ void read8(const char* p, int rd, short8 (&fr)[8]) {
#pragma unroll
    for (int i = 0; i < 8; ++i)
        fr[i] = *(const short8*)(p + rd + i * 1024);   // i*16 rows * 64 B
}

__device__ __forceinline__ void mfma64(const short8 (&af)[8], const short8 (&bf)[8],
                                       f32x4 (&acc)[8][8]) {
    __builtin_amdgcn_s_setprio(1);
#pragma unroll
    for (int i = 0; i < 8; ++i)
#pragma unroll
        for (int j = 0; j < 8; ++j)
            acc[i][j] = __builtin_amdgcn_mfma_f32_16x16x32_bf16(
                af[i], bf[j], acc[i][j], 0, 0, 0);
    __builtin_amdgcn_s_setprio(0);
}

// ---- kernel 3: C = A(MxK)*Bt(NxK)^T + bias ----
// R12 (= R11 + lgkmcnt fix): 4 waves (1/SIMD), 256^2 tile, BK=32, 4-slot LDS
// pipeline, one-phase read-ahead, 1 barrier/phase.
// Phase p: MFMA(tile p, frags read @p-1) | read frags(p+1) | stage tile p+3
//          | vmcnt(8) [t(p+2) retired BEFORE barrier => resident for all
//          waves when read at p+1] | barrier.
// LGKM(15) retires the 16 CUR frags (issued @p-1), keeps >=15 of own 16 in flight.
__global__ __launch_bounds__(256, 1) void gemm_pipe4(const ushort_t* __restrict__ A,
                                                     const ushort_t* __restrict__ Bt,
                                                     const float* __restrict__ bias,
                                                     float* __restrict__ C) {
    __shared__ __align__(16) ushort_t lds_a[4][SLOT];   // 64 KiB
    __shared__ __align__(16) ushort_t lds_b[4][SLOT];   // 64 KiB

    // 2D XCD-rectangle swizzle (R5: FETCH 542->197 MB)
    const int bid = blockIdx.x;                  // 0..1023
    const int xc = bid & 7;                      // XCD
    const int qq = bid >> 3;                     // 0..127
    const int mt = ((xc >> 1) << 2) + (qq & 3) + (((qq >> 5) & 1) << 4);
    const int nt = ((xc & 1) << 3) + ((qq >> 2) & 7) + (((qq >> 6) & 1) << 4);
    const int m0 = mt * BM;
    const int n0 = nt * BN;

    const int tid = threadIdx.x;
    const int lane = tid & 63;
    const int wid = tid >> 6;              // 0..3
    const int wm = wid >> 1, wn = wid & 1; // 2x2 wave grid; wave out 128x128
    const int lane15 = lane & 15, laneq = lane >> 4;

    // --- fragment read base: row = W + lane15, granule = laneq ^ (row&3) ---
    const int rdA = (wm * 128 + lane15) * 64 + ((laneq ^ (lane15 & 3)) << 4);
    const int rdB = (wn * 128 + lane15) * 64 + ((laneq ^ (lane15 & 3)) << 4);

    // --- staging: thread covers LDS granules {tid, +256, +512, +768} ---
    // granule G: row=G>>2 (=r+64h), col' = G&3 (=tid&3); global col = col'^(row&3)
    const int r = tid >> 2;                          // 0..63
    const int cg = (tid & 3) ^ (r & 3);              // inverse-swizzled k-granule
    const ushort_t* Ab = A  + (size_t)(m0 + r) * K_DIM + cg * 8;
    const ushort_t* Bb = Bt + (size_t)(n0 + r) * K_DIM + cg * 8;
    const int dq = tid * 16;

#define STAGE(t) do { \
        const int _sl = (t) & 3; \
        char* _da = (char*)&lds_a[_sl][0] + dq; \
        char* _db = (char*)&lds_b[_sl][0] + dq; \
        const ushort_t* _ga = Ab + (size_t)(t) * BK; \
        const ushort_t* _gb = Bb + (size_t)(t) * BK; \
        async_copy16(_ga,              _da); \
        async_copy16(_ga + KROW64,     _da + 4096); \
        async_copy16(_ga + 2 * KROW64, _da + 8192); \
        async_copy16(_ga + 3 * KROW64, _da + 12288); \
        async_copy16(_gb,              _db); \
        async_copy16(_gb + KROW64,     _db + 4096); \
        async_copy16(_gb + 2 * KROW64, _db + 8192); \
        async_copy16(_gb + 3 * KROW64, _db + 12288); \
    } while (0)

    f32x4 acc[8][8];
#pragma unroll
    for (int i = 0; i < 8; ++i)
#pragma unroll
        for (int j = 0; j < 8; ++j) acc[i][j] = (f32x4){0.f, 0.f, 0.f, 0.f};

    short8 afC[8], bfC[8], afN[8], bfN[8];

    // --- prologue: stage t0,t1,t2 (24 loads); t0,t1 resident; read frags(0) ---
    STAGE(0); STAGE(1); STAGE(2);
    VMC(8);            // retire t0,t1; keep t2
    BAR();
    read8((const char*)&lds_a[0][0], rdA, afC);
    read8((const char*)&lds_b[0][0], rdB, bfC);

    // steady phase: reads(p+1) -> NXT; stage(p+3); LGKM(15); MFMA(CUR); vmcnt(8); BAR
#define PHASE_MAIN(p, AC, BC, AN, BN) do { \
        read8((const char*)&lds_a[((p) + 1) & 3][0], rdA, AN); \
        read8((const char*)&lds_b[((p) + 1) & 3][0], rdB, BN); \
        STAGE((p) + 3); \
        LGKM(15); \
        mfma64(AC, BC, acc); \
        VMC(8); \
        BAR(); \
    } while (0)

    for (int p = 0; p < 60; p += 2) {
        PHASE_MAIN(p,     afC, bfC, afN, bfN);
        PHASE_MAIN(p + 1, afN, bfN, afC, bfC);
    }
    // p=60 (CUR=C): reads(61); stage(63); vmcnt(8)
    read8((const char*)&lds_a[61 & 3][0], rdA, afN);
    read8((const char*)&lds_b[61 & 3][0], rdB, bfN);
    STAGE(63);
    LGKM(15); mfma64(afC, bfC, acc); VMC(8); BAR();
    // p=61 (CUR=N): reads(62); vmcnt(0) [t63 resident for p=62 reads]
    read8((const char*)&lds_a[62 & 3][0], rdA, afC);
    read8((const char*)&lds_b[62 & 3][0], rdB, bfC);
    LGKM(15); mfma64(afN, bfN, acc); VMC(0); BAR();
    // p=62 (CUR=C): reads(63)
    read8((const char*)&lds_a[63 & 3][0], rdA, afN);
    read8((const char*)&lds_b[63 & 3][0], rdB, bfN);
    LGKM(15); mfma64(afC, bfC, acc); BAR();
    // p=63 (CUR=N)
    LGKM(0); mfma64(afN, bfN, acc);

    // --- epilogue: bias + f32 store ---
#pragma unroll
    for (int jg = 0; jg < 8; ++jg) {
        const int col = n0 + wn * 128 + jg * 16 + lane15;
        const float bv = bias[col];
#pragma unroll
        for (int ig = 0; ig < 8; ++ig) {
            const int row = m0 + wm * 128 + ig * 16 + laneq * 4;
            f32x4 v = acc[ig][jg];
#pragma unroll
            for (int q2 = 0; q2 < 4; ++q2)
                C[(size_t)(row + q2) * N_DIM + col] = v[q2] + bv;
        }
    }
#undef STAGE
#undef PHASE_MAIN
}

extern "C" void kernel_launch(void* const* d_in, const int* in_sizes, int n_in,
                              void* d_out, int out_size, void* d_ws, size_t ws_size,
                              hipStream_t stream) {
    const float* x = (const float*)d_in[0];
    const float* codebook = (const float*)d_in[1];
    const int* indices = (const int*)d_in[2];      // harness: integer -> int32
    const float* bias = (const float*)d_in[3];
    float* out = (float*)d_out;

    ushort_t* A  = (ushort_t*)d_ws;                               // 32 MB
    ushort_t* Bt = (ushort_t*)d_ws + (size_t)M_DIM * K_DIM;       // 32 MB

    convert_x<<<dim3(M_DIM * K_DIM / (256 * 8)), 256, 0, stream>>>(x, A);
    dequant_wt<<<dim3(1024, 8), 256, 0, stream>>>(indices, codebook, Bt);
    gemm_pipe4<<<dim3((M_DIM / BM) * (N_DIM / BN)), 256, 0, stream>>>(A, Bt, bias, out);
}

// Round 13
// 310.742 us; speedup vs baseline: 1.9263x; 1.0799x over previous
//
#include <hip/hip_runtime.h>
#include <hip/hip_bf16.h>

typedef unsigned short ushort_t;
typedef __attribute__((ext_vector_type(8))) short short8;
typedef __attribute__((ext_vector_type(4))) float f32x4;

#define M_DIM 8192
#define N_DIM 8192
#define K_DIM 2048
#define BM 256
#define BN 256
#define BK 32
#define NT (K_DIM / BK)        // 64 K-tiles
#define SLOTE 8192             // ushort per 16 KiB slot

__device__ __forceinline__ ushort_t f2bf(float f) {
    union { float f; unsigned u; } v; v.f = f;
    unsigned r = v.u + 0x7fffu + ((v.u >> 16) & 1u);   // RNE
    return (ushort_t)(r >> 16);
}

__device__ __forceinline__ void async_copy16(const void* g, void* l) {
    __builtin_amdgcn_global_load_lds(
        (const __attribute__((address_space(1))) void*)g,
        (__attribute__((address_space(3))) void*)l, 16, 0, 0);
}

#define BAR() __builtin_amdgcn_s_barrier()
#define LGKM(n) do { asm volatile("s_waitcnt lgkmcnt(" #n ")" ::: "memory"); \
                     __builtin_amdgcn_sched_barrier(0); } while (0)
#define VMC(n) do { asm volatile("s_waitcnt vmcnt(" #n ")" ::: "memory"); \
                    __builtin_amdgcn_sched_barrier(0); } while (0)

// ---- kernel 1: x (f32) -> A (bf16) ----
__global__ __launch_bounds__(256) void convert_x(const float* __restrict__ x,
                                                 ushort_t* __restrict__ A) {
    int t = blockIdx.x * 256 + threadIdx.x;
    const float4* p = (const float4*)x + (size_t)t * 2;
    float4 a = p[0], b = p[1];
    short8 o;
    o[0] = (short)f2bf(a.x); o[1] = (short)f2bf(a.y);
    o[2] = (short)f2bf(a.z); o[3] = (short)f2bf(a.w);
    o[4] = (short)f2bf(b.x); o[5] = (short)f2bf(b.y);
    o[6] = (short)f2bf(b.z); o[7] = (short)f2bf(b.w);
    *(short8*)(A + (size_t)t * 8) = o;
}

// ---- kernel 2: codebook gather -> Bt (bf16, N x K layout) ----
__global__ __launch_bounds__(256) void dequant_wt(const int* __restrict__ indices,
                                                  const float* __restrict__ codebook,
                                                  ushort_t* __restrict__ Bt) {
    int g = blockIdx.x;                       // column group 0..1023
    int i = blockIdx.y * 256 + threadIdx.x;   // K row 0..2047
    int idx = indices[(size_t)i * 1024 + g];
    const float4* cb = (const float4*)(codebook + (size_t)idx * 8);
    float4 lo = cb[0], hi = cb[1];
    size_t base = (size_t)g * 8 * K_DIM + i;
    Bt[base + 0 * K_DIM] = f2bf(lo.x);
    Bt[base + 1 * K_DIM] = f2bf(lo.y);
    Bt[base + 2 * K_DIM] = f2bf(lo.z);
    Bt[base + 3 * K_DIM] = f2bf(lo.w);
    Bt[base + 4 * K_DIM] = f2bf(hi.x);
    Bt[base + 5 * K_DIM] = f2bf(hi.y);
    Bt[base + 6 * K_DIM] = f2bf(hi.z);
    Bt[base + 7 * K_DIM] = f2bf(hi.w);
}

// ---- helpers ----
__device__ __forceinline__ void read8(const char* p, int rd, short8 (&fr)[8]) {
#pragma unroll
    for (int i = 0; i < 8; ++i)
        fr[i] = *(const short8*)(p + rd + i * 1024);   // 16 rows = 8 wrows = 1024 B
}

__device__ __forceinline__ void read4(const char* p, int rd, short8 (&fr)[4]) {
#pragma unroll
    for (int j = 0; j < 4; ++j)
        fr[j] = *(const short8*)(p + rd + j * 1024);
}

__device__ __forceinline__ void mfma32(const short8 (&af)[8], const short8 (&bf)[4],
                                       f32x4 (&acc)[8][4]) {
    __builtin_amdgcn_s_setprio(1);
#pragma unroll
    for (int i = 0; i < 8; ++i)
#pragma unroll
        for (int j = 0; j < 4; ++j)
            acc[i][j] = __builtin_amdgcn_mfma_f32_16x16x32_bf16(
                af[i], bf[j], acc[i][j], 0, 0, 0);
    __builtin_amdgcn_s_setprio(0);
}

// ---- kernel 3: C = A(MxK)*Bt(NxK)^T + bias ----
// R13: 8 waves (2/SIMD TLP), wave out 128x64, BK=32, 4-slot LDS pipeline,
// full one-phase read-ahead, 1 barrier/phase, paired-row swizzle (2-way banks).
// Phase p: read frags(p+1) | stage t(p+3) | LGKM(12) [retire frags(p)] |
//          MFMA(p) | VMC(4) [retire t(p+2)] | BAR.
// LDS layout: phys(row,kg) = (row>>1)*128 + ((((row&1)<<2)|kg)^((row>>1)&7))*16.
__global__ __launch_bounds__(512, 2) void gemm_ra8(const ushort_t* __restrict__ A,
                                                   const ushort_t* __restrict__ Bt,
                                                   const float* __restrict__ bias,
                                                   float* __restrict__ C) {
    __shared__ __align__(16) ushort_t lds_a[4][SLOTE];   // 64 KiB
    __shared__ __align__(16) ushort_t lds_b[4][SLOTE];   // 64 KiB

    // 2D XCD-rectangle swizzle (R5: FETCH 542->197 MB)
    const int bid = blockIdx.x;                  // 0..1023
    const int xc = bid & 7;
    const int qq = bid >> 3;
    const int mt = ((xc >> 1) << 2) + (qq & 3) + (((qq >> 5) & 1) << 4);
    const int nt = ((xc & 1) << 3) + ((qq >> 2) & 7) + (((qq >> 6) & 1) << 4);
    const int m0 = mt * BM;
    const int n0 = nt * BN;

    const int tid = threadIdx.x;
    const int lane = tid & 63;
    const int wid = tid >> 6;              // 0..7
    const int wm = wid >> 2, wn = wid & 3; // 2x4 wave grid; wave out 128x64
    const int lane15 = lane & 15, laneq = lane >> 4;

    // --- fragment read bases (swizzled): 16 lanes -> 8 bank-quads x2 = free ---
    const int l2 = lane15 >> 1;
    const int gsw = (((((lane15 & 1) << 2) | laneq) ^ l2) << 4);
    const int rdA = (wm * 64 + l2) * 128 + gsw;   // wave rows wm*128..+127
    const int rdB = (wn * 32 + l2) * 128 + gsw;   // wave cols wn*64..+63

    // --- staging: dest granule D=tid (+512); inverse-swizzled source coords ---
    const int e = (tid & 7) ^ ((tid >> 3) & 7);
    const int kgs = e & 3;
    const int row0 = ((tid >> 3) << 1) + ((e >> 2) & 1);   // 0..127
    const ushort_t* Ab = A  + (size_t)(m0 + row0) * K_DIM + kgs * 8;
    const ushort_t* Bb = Bt + (size_t)(n0 + row0) * K_DIM + kgs * 8;
    const int dq = tid * 16;
    const size_t R128 = (size_t)128 * K_DIM;

#define STAGE(t) do { const int _sl = (t) & 3; \
        char* _da = (char*)&lds_a[_sl][0] + dq; \
        char* _db = (char*)&lds_b[_sl][0] + dq; \
        const ushort_t* _ga = Ab + (size_t)(t) * BK; \
        const ushort_t* _gb = Bb + (size_t)(t) * BK; \
        async_copy16(_ga,        _da); \
        async_copy16(_ga + R128, _da + 8192); \
        async_copy16(_gb,        _db); \
        async_copy16(_gb + R128, _db + 8192); \
    } while (0)

    f32x4 acc[8][4];
#pragma unroll
    for (int i = 0; i < 8; ++i)
#pragma unroll
        for (int j = 0; j < 4; ++j) acc[i][j] = (f32x4){0.f, 0.f, 0.f, 0.f};

    short8 afC[8], afN[8], bfC[4], bfN[4];

    // --- prologue: stage t0,t1,t2; retire t0,t1; read frags(0) ---
    STAGE(0); STAGE(1); STAGE(2);
    VMC(4);
    BAR();
    read8((const char*)&lds_a[0][0], rdA, afC);
    read4((const char*)&lds_b[0][0], rdB, bfC);

#define PHASE(p, AC, BC, AN, BN_) do { \
        read8((const char*)&lds_a[((p) + 1) & 3][0], rdA, AN); \
        read4((const char*)&lds_b[((p) + 1) & 3][0], rdB, BN_); \
        STAGE((p) + 3); \
        LGKM(12); \
        mfma32(AC, BC, acc); \
        VMC(4); \
        BAR(); \
    } while (0)

    for (int p = 0; p < 60; p += 2) {          // p = 0..59
        PHASE(p,     afC, bfC, afN, bfN);
        PHASE(p + 1, afN, bfN, afC, bfC);
    }
    // p=60: stage t63 (last), VMC(4) retires t62
    PHASE(60, afC, bfC, afN, bfN);
    // p=61: no stage; VMC(0) retires t63 (needed for reads @62)
    read8((const char*)&lds_a[62 & 3][0], rdA, afC);
    read4((const char*)&lds_b[62 & 3][0], rdB, bfC);
    LGKM(12); mfma32(afN, bfN, acc); VMC(0); BAR();
    // p=62
    read8((const char*)&lds_a[63 & 3][0], rdA, afN);
    read4((const char*)&lds_b[63 & 3][0], rdB, bfN);
    LGKM(12); mfma32(afC, bfC, acc); BAR();
    // p=63
    LGKM(0); mfma32(afN, bfN, acc);
#undef PHASE

    // --- epilogue: bias + f32 store ---
#pragma unroll
    for (int jg = 0; jg < 4; ++jg) {
        const int col = n0 + wn * 64 + jg * 16 + lane15;
        const float bv = bias[col];
#pragma unroll
        for (int ig = 0; ig < 8; ++ig) {
            const int row = m0 + wm * 128 + ig * 16 + laneq * 4;
            f32x4 v = acc[ig][jg];
#pragma unroll
            for (int q2 = 0; q2 < 4; ++q2)
                C[(size_t)(row + q2) * N_DIM + col] = v[q2] + bv;
        }
    }
#undef STAGE
}

extern "C" void kernel_launch(void* const* d_in, const int* in_sizes, int n_in,
                              void* d_out, int out_size, void* d_ws, size_t ws_size,
                              hipStream_t stream) {
    const float* x = (const float*)d_in[0];
    const float* codebook = (const float*)d_in[1];
    const int* indices = (const int*)d_in[2];      // harness: integer -> int32
    const float* bias = (const float*)d_in[3];
    float* out = (float*)d_out;

    ushort_t* A  = (ushort_t*)d_ws;                               // 32 MB
    ushort_t* Bt = (ushort_t*)d_ws + (size_t)M_DIM * K_DIM;       // 32 MB

    convert_x<<<dim3(M_DIM * K_DIM / (256 * 8)), 256, 0, stream>>>(x, A);
    dequant_wt<<<dim3(1024, 8), 256, 0, stream>>>(indices, codebook, Bt);
    gemm_ra8<<<dim3((M_DIM / BM) * (N_DIM / BN)), 512, 0, stream>>>(A, Bt, bias, out);
}